// Round 4
// baseline (631.484 us; speedup 1.0000x reference)
//
#include <hip/hip_runtime.h>
#include <hip/hip_bf16.h>

#define BN 8
#define HN 128
#define WN 128
#define CN 256
#define DTC 0.2f
#define EPSV 1e-3f
#define NTH 1024

#define SJ 32      // staged channel rows; row j <-> cj = c0-8+j
#define SW 130     // phys cols: 0 = reflect(w=1), 1..128 = w0..127, 129 = reflect(w=126)

// ---- dtype-generic helpers (compute stays f32) ----
__device__ __forceinline__ float ldf(const float* p)            { return *p; }
__device__ __forceinline__ float ldf(const __hip_bfloat16* p)   { return __bfloat162float(*p); }
__device__ __forceinline__ __hip_bfloat16 ldb(const float* p)          { return __float2bfloat16(*p); }
__device__ __forceinline__ __hip_bfloat16 ldb(const __hip_bfloat16* p) { return *p; }

__device__ __forceinline__ __hip_bfloat162 ldb2(const float* p) {
    __hip_bfloat162 r; r.x = __float2bfloat16(p[0]); r.y = __float2bfloat16(p[1]); return r;
}
__device__ __forceinline__ __hip_bfloat162 ldb2(const __hip_bfloat16* p) {
    return *(const __hip_bfloat162*)p;
}
__device__ __forceinline__ void st4(float* p, float4 v) { *(float4*)p = v; }
__device__ __forceinline__ void st4(__hip_bfloat16* p, float4 v) {
    __hip_bfloat162 lo; lo.x = __float2bfloat16(v.x); lo.y = __float2bfloat16(v.y);
    __hip_bfloat162 hi; hi.x = __float2bfloat16(v.z); hi.y = __float2bfloat16(v.w);
    *(__hip_bfloat162*)p = lo; *(__hip_bfloat162*)(p + 2) = hi;
}

// ---- dtype probe: bf16 exponent band test on raw u32 words ----
__global__ void probe_kernel(const unsigned int* __restrict__ s0w, int* __restrict__ flag) {
    __shared__ int cnt;
    if (threadIdx.x == 0) cnt = 0;
    __syncthreads();
    int local = 0;
    for (int i = threadIdx.x; i < 4096; i += 256) {
        unsigned int e = (s0w[i] >> 7) & 0xFF;
        if (e >= 118 && e <= 130) local++;
    }
    atomicAdd(&cnt, local);
    __syncthreads();
    if (threadIdx.x == 0) *flag = (cnt > 2048) ? 1 : 0;   // 1 = bf16, 0 = f32
}

template <typename T>
__global__ __launch_bounds__(NTH, 8)   // 64-VGPR cap -> 2 blocks/CU (LDS also caps at 2)
void diffusion_kernel(const T* __restrict__ s0,  const T* __restrict__ wg,  const T* __restrict__ wg1,
                      const T* __restrict__ g_gamma,  const T* __restrict__ g_beta,
                      const T* __restrict__ g_mean,   const T* __restrict__ g_var,
                      const T* __restrict__ g1_gamma, const T* __restrict__ g1_beta,
                      const T* __restrict__ g1_mean,  const T* __restrict__ g1_var,
                      const T* __restrict__ out_gamma, const T* __restrict__ out_beta,
                      const T* __restrict__ out_mean,  const T* __restrict__ out_var,
                      T* __restrict__ out,
                      const int* __restrict__ flag, int want)
{
    if (flag && *flag != want) return;   // dtype dispatch

    __shared__ __align__(16) __hip_bfloat16 s0s[3][SJ][SW];   // 24960 B
    __shared__ float wgt[2][9][SJ];                           //  2304 B
    __shared__ float bnp[4][SJ];                              //   512 B
    __shared__ float obn[2][16];                              //   128 B
    __shared__ __align__(16) float r2[2*28*128];              // 28672 B : gb/g1b then hA/hB

    const int tid = threadIdx.x;
    const int bid = blockIdx.x;
    const int h     = bid & 127;
    const int bc    = bid >> 7;
    const int chunk = bc & 15;
    const int b     = bc >> 4;
    const int c0    = chunk << 4;

    const int   rT   = (h > 0)   ? h - 1 : 1;      // sobel reflect rows
    const int   rB   = (h < 127) ? h + 1 : 126;
    const float topf = (h > 0)   ? 1.f : 0.f;      // conv zero-pad flags (folded into wgt)
    const float botf = (h < 127) ? 1.f : 0.f;

    const size_t base = (size_t)b * HN * WN * CN;
    const int rowIdx[3] = { rT, h, rB };

    // ---- stage s0: 3 rows x 16 channel-pairs x 128 w, paired global loads ----
    #pragma unroll
    for (int k = 0; k < 6; ++k) {
        int e  = tid + k*NTH;                  // < 6144
        int jp = e & 15;
        int w  = (e >> 4) & 127;
        int r  = e >> 11;
        int cj = (c0 - 8 + 2*jp) & 255;        // even; cj+1 adjacent in memory
        __hip_bfloat162 p = ldb2(&s0[base + ((size_t)rowIdx[r]*WN + w)*CN + cj]);
        s0s[r][2*jp  ][w+1] = p.x;
        s0s[r][2*jp+1][w+1] = p.y;
    }
    if (tid < 192) {                           // reflect pad columns from global
        int r = tid >> 6, rest = tid & 63, j = rest >> 1, side = rest & 1;
        int ph = side ? 129 : 0, sw = side ? 126 : 1;
        int cj = (c0 - 8 + j) & 255;
        s0s[r][j][ph] = ldb(&s0[base + ((size_t)rowIdx[r]*WN + sw)*CN + cj]);
    }
    if (tid < 288) {                           // weights, H zero-pad folded in
        int t9 = tid >> 5, j = tid & 31;
        int cj = (c0 - 8 + j) & 255;
        float rf = (t9 < 3) ? topf : ((t9 >= 6) ? botf : 1.f);
        wgt[0][t9][j] = ldf(&wg [t9*CN + cj]) * rf;
        wgt[1][t9][j] = ldf(&wg1[t9*CN + cj]) * rf;
    }
    if (tid < 32) {                            // folded BN params
        int cj = (c0 - 8 + tid) & 255;
        float s  = ldf(&g_gamma[cj])  * rsqrtf(ldf(&g_var[cj])  + EPSV);
        bnp[0][tid] = s;
        bnp[1][tid] = ldf(&g_beta[cj])  - ldf(&g_mean[cj])  * s;
        float s1 = ldf(&g1_gamma[cj]) * rsqrtf(ldf(&g1_var[cj]) + EPSV);
        bnp[2][tid] = s1;
        bnp[3][tid] = ldf(&g1_beta[cj]) - ldf(&g1_mean[cj]) * s1;
    }
    if (tid < 16) {
        int c = c0 + tid;
        float s = ldf(&out_gamma[c]) * rsqrtf(ldf(&out_var[c]) + EPSV);
        obn[0][tid] = s;
        obn[1][tid] = ldf(&out_beta[c]) - ldf(&out_mean[c]) * s;
    }
    __syncthreads();

    float* gb  = r2;            // [28][128]
    float* g1b = r2 + 3584;

    // Unified per-thread mapping: row l = tid>>5 (channel c0-6+l), quad w0 = 4*(tid&31).
    const int wq = tid & 31, l = tid >> 5, w0 = wq << 2;
    const bool p1act = (l < 28);               // conv rows 0..27
    const bool act   = (l >= 1 && l <= 26);    // coefficient / jacobi rows

    float a0[4], aE[4], amx[4], apx[4], amy[4], apy[4], aS[4], Dv[4], fsv[4], gq[4];

    if (p1act) {
        const int j = l + 2;
        // ---- one-shot packed read of the 3x6 s0 tile (reused by conv AND sobel) ----
        float c_[3][6];
        #pragma unroll
        for (int r = 0; r < 3; ++r) {
            float2 p0 = __bfloat1622float2(*(const __hip_bfloat162*)&s0s[r][j][w0]);
            float2 p1 = __bfloat1622float2(*(const __hip_bfloat162*)&s0s[r][j][w0+2]);
            float2 p2 = __bfloat1622float2(*(const __hip_bfloat162*)&s0s[r][j][w0+4]);
            c_[r][0] = p0.x; c_[r][1] = p0.y; c_[r][2] = p1.x;
            c_[r][3] = p1.y; c_[r][4] = p2.x; c_[r][5] = p2.y;
        }
        // ---- conv (zero-pad in W via edge-tap zeroing) + BN + relu ----
        float ag[4] = {0.f,0.f,0.f,0.f}, a1[4] = {0.f,0.f,0.f,0.f};
        #pragma unroll
        for (int r = 0; r < 3; ++r) {
            float t0 = (wq == 0)  ? 0.f : c_[r][0];
            float t5 = (wq == 31) ? 0.f : c_[r][5];
            float wa = wgt[0][r*3+0][j], wb = wgt[0][r*3+1][j], wc = wgt[0][r*3+2][j];
            float ua = wgt[1][r*3+0][j], ub = wgt[1][r*3+1][j], uc = wgt[1][r*3+2][j];
            ag[0] += t0*wa       + c_[r][1]*wb + c_[r][2]*wc;
            ag[1] += c_[r][1]*wa + c_[r][2]*wb + c_[r][3]*wc;
            ag[2] += c_[r][2]*wa + c_[r][3]*wb + c_[r][4]*wc;
            ag[3] += c_[r][3]*wa + c_[r][4]*wb + t5*wc;
            a1[0] += t0*ua       + c_[r][1]*ub + c_[r][2]*uc;
            a1[1] += c_[r][1]*ua + c_[r][2]*ub + c_[r][3]*uc;
            a1[2] += c_[r][2]*ua + c_[r][3]*ub + c_[r][4]*uc;
            a1[3] += c_[r][3]*ua + c_[r][4]*ub + t5*uc;
        }
        float g1q[4];
        float bs = bnp[0][j], bb = bnp[1][j], cs = bnp[2][j], cb2 = bnp[3][j];
        #pragma unroll
        for (int k = 0; k < 4; ++k) {
            gq[k]  = fmaxf(ag[k]*bs + bb,  0.f);
            g1q[k] = fmaxf(a1[k]*cs + cb2, 0.f);
        }
        st4(&gb [l*128 + w0], make_float4(gq[0],  gq[1],  gq[2],  gq[3]));
        *(float4*)&g1b[l*128 + w0] = make_float4(g1q[0], g1q[1], g1q[2], g1q[3]);

        // ---- own-row sobel + 6 of 7 coefficients, pre-barrier ----
        if (act) {
            #pragma unroll
            for (int k = 0; k < 4; ++k) {
                float gy = (c_[2][k] + 2.f*c_[2][k+1] + c_[2][k+2])
                         - (c_[0][k] + 2.f*c_[0][k+1] + c_[0][k+2]);
                float gx = (c_[0][k+2] + 2.f*c_[1][k+2] + c_[2][k+2])
                         - (c_[0][k]   + 2.f*c_[1][k]   + c_[2][k]);
                float Bx = DTC / (gy*gy*0.25f + 1.f);
                float By = DTC / (gx*gx*0.25f + 1.f);
                float Ax = gq[k]*DTC, Ay = g1q[k]*DTC;
                float dv = 1.f / (1.f + 2.f*Bx + 2.f*By);
                Dv[k]  = dv;
                a0[k]  = 2.f*dv - 1.f;            // Dv*(1-2Bx-2By)
                amx[k] = dv*(2.f*Bx - Ax);
                apx[k] = dv*(2.f*Bx + Ax);
                amy[k] = dv*(2.f*By - Ay);
                apy[k] = dv*(2.f*By + Ay);
                fsv[k] = c_[1][k+1];
                aS[k]  = dv*(2.f*DTC)*fsv[k];
            }
        }
    }
    __syncthreads();

    // ---- pass 2: only aE needs neighbors ----
    if (act) {
        float  gL  = gb[l*128 + ((w0 - 1) & 127)];
        float  gR  = gb[l*128 + ((w0 + 4) & 127)];
        float4 g1u = *(float4*)&g1b[(l-1)*128 + w0];
        float4 g1d = *(float4*)&g1b[(l+1)*128 + w0];
        float ux0 = 0.5f*(gL    - gq[1]);
        float ux1 = 0.5f*(gq[0] - gq[2]);
        float ux2 = 0.5f*(gq[1] - gq[3]);
        float ux3 = 0.5f*(gq[2] - gR);
        aE[0] = (2.f*DTC)*Dv[0]*(ux0 + 0.5f*(g1u.x - g1d.x));
        aE[1] = (2.f*DTC)*Dv[1]*(ux1 + 0.5f*(g1u.y - g1d.y));
        aE[2] = (2.f*DTC)*Dv[2]*(ux2 + 0.5f*(g1u.z - g1d.z));
        aE[3] = (2.f*DTC)*Dv[3]*(ux3 + 0.5f*(g1u.w - g1d.w));
    }
    __syncthreads();   // gb/g1b reads done; r2 becomes hA/hB

    // ---- pass 3: init h = h0 = fsrc; zero the sacrificial pad rows 0,27 ----
    if (act) {
        float4 f4 = make_float4(fsv[0], fsv[1], fsv[2], fsv[3]);
        *(float4*)&r2[l*128 + w0]        = f4;   // hA
        *(float4*)&r2[3584 + l*128 + w0] = f4;   // hB
    } else if (l == 0 || l == 27) {
        float4 z = make_float4(0.f, 0.f, 0.f, 0.f);
        *(float4*)&r2[l*128 + w0]        = z;
        *(float4*)&r2[3584 + l*128 + w0] = z;
    }
    __syncthreads();

    // ---- pass 4: 5 Jacobi iterations, immediate LDS addressing ----
    float* bU = &r2[(l-1)*128 + w0];                   // row above (channel-1)
    float* bM = &r2[l*128 + ((w0 - 1) & 127)];         // left edge (circular W)
    float* bP = &r2[l*128 + ((w0 + 4) & 127)];         // right edge
    #pragma unroll
    for (int n = 0; n < 5; ++n) {
        const int co = (n & 1) ? 0 : 3584;   // cur buffer float offset
        const int po = 3584 - co;            // prv (receives h_{n+1})
        if (act) {
            float4 up = *(float4*)(bU + co);
            float4 hc = *(float4*)(bU + co + 128);
            float4 dn = *(float4*)(bU + co + 256);
            float4 h0 = *(float4*)(bU + po + 128);
            float  eL = bM[co];
            float  eR = bP[co];
            float4 nw;
            nw.x = a0[0]*h0.x - aE[0]*hc.x + amx[0]*eL   + apx[0]*hc.y + amy[0]*up.x + apy[0]*dn.x + aS[0];
            nw.y = a0[1]*h0.y - aE[1]*hc.y + amx[1]*hc.x + apx[1]*hc.z + amy[1]*up.y + apy[1]*dn.y + aS[1];
            nw.z = a0[2]*h0.z - aE[2]*hc.z + amx[2]*hc.y + apx[2]*hc.w + amy[2]*up.z + apy[2]*dn.z + aS[2];
            nw.w = a0[3]*h0.w - aE[3]*hc.w + amx[3]*hc.z + apx[3]*eR   + amy[3]*up.w + apy[3]*dn.w + aS[3];
            *(float4*)(bU + po + 128) = nw;
        }
        __syncthreads();
    }
    // final h is in hA = r2 (rows 1..26); core channels are rows 6..21

    // ---- pass 5: out = relu(bn(h)), float4 over channels ----
    if (tid < 512) {
        int cq = tid & 3, w5 = tid >> 2;       // 4 channel-quads x 128 w
        int ib = cq << 2;
        float4 v;
        v.x = r2[(6 + ib    )*128 + w5];
        v.y = r2[(6 + ib + 1)*128 + w5];
        v.z = r2[(6 + ib + 2)*128 + w5];
        v.w = r2[(6 + ib + 3)*128 + w5];
        v.x = fmaxf(v.x*obn[0][ib  ] + obn[1][ib  ], 0.f);
        v.y = fmaxf(v.y*obn[0][ib+1] + obn[1][ib+1], 0.f);
        v.z = fmaxf(v.z*obn[0][ib+2] + obn[1][ib+2], 0.f);
        v.w = fmaxf(v.w*obn[0][ib+3] + obn[1][ib+3], 0.f);
        st4(&out[(((size_t)b*HN + h)*WN + w5)*CN + c0 + ib], v);
    }
}

extern "C" void kernel_launch(void* const* d_in, const int* in_sizes, int n_in,
                              void* d_out, int out_size, void* d_ws, size_t ws_size,
                              hipStream_t stream) {
    dim3 grid(BN * 16 * HN);   // 16384 blocks; consecutive blocks walk h (L2 row reuse)

    if (ws_size >= 4) {
        int* flag = (int*)d_ws;
        probe_kernel<<<1, 256, 0, stream>>>((const unsigned int*)d_in[0], flag);

        diffusion_kernel<float><<<grid, NTH, 0, stream>>>(
            (const float*)d_in[0], (const float*)d_in[1], (const float*)d_in[2],
            (const float*)d_in[3], (const float*)d_in[4], (const float*)d_in[5], (const float*)d_in[6],
            (const float*)d_in[7], (const float*)d_in[8], (const float*)d_in[9], (const float*)d_in[10],
            (const float*)d_in[11], (const float*)d_in[12], (const float*)d_in[13], (const float*)d_in[14],
            (float*)d_out, flag, 0);

        diffusion_kernel<__hip_bfloat16><<<grid, NTH, 0, stream>>>(
            (const __hip_bfloat16*)d_in[0], (const __hip_bfloat16*)d_in[1], (const __hip_bfloat16*)d_in[2],
            (const __hip_bfloat16*)d_in[3], (const __hip_bfloat16*)d_in[4], (const __hip_bfloat16*)d_in[5], (const __hip_bfloat16*)d_in[6],
            (const __hip_bfloat16*)d_in[7], (const __hip_bfloat16*)d_in[8], (const __hip_bfloat16*)d_in[9], (const __hip_bfloat16*)d_in[10],
            (const __hip_bfloat16*)d_in[11], (const __hip_bfloat16*)d_in[12], (const __hip_bfloat16*)d_in[13], (const __hip_bfloat16*)d_in[14],
            (__hip_bfloat16*)d_out, flag, 1);
    } else {
        diffusion_kernel<float><<<grid, NTH, 0, stream>>>(
            (const float*)d_in[0], (const float*)d_in[1], (const float*)d_in[2],
            (const float*)d_in[3], (const float*)d_in[4], (const float*)d_in[5], (const float*)d_in[6],
            (const float*)d_in[7], (const float*)d_in[8], (const float*)d_in[9], (const float*)d_in[10],
            (const float*)d_in[11], (const float*)d_in[12], (const float*)d_in[13], (const float*)d_in[14],
            (float*)d_out, nullptr, 0);
    }
}